// Round 3
// baseline (216.534 us; speedup 1.0000x reference)
//
#include <hip/hip_runtime.h>
#include <math.h>

// Problem constants (fixed by setup_inputs)
#define D 1024
#define B 32
#define N 1024          // patches per image (32x32)
#define SIDE 32
#define OUT 512
#define NLAYER 4
#define TAU_INV (1.0f/0.07f)
#define EPS_NORM 1e-12f

__device__ __forceinline__ float wave_sum(float s) {
#pragma unroll
    for (int m = 32; m; m >>= 1) s += __shfl_xor(s, m);
    return s;
}

// ---------------------------------------------------------------------------
// Kernel 1: cls logits (computes its own w_cls norms).
// One wave per (l,b) row; 128 waves -> 32 blocks x 256.
// ---------------------------------------------------------------------------
__global__ void cls_kernel(const float* c0, const float* wc0,
                           const float* c1, const float* wc1,
                           const float* c2, const float* wc2,
                           const float* c3, const float* wc3,
                           float* out) {
    int wid = blockIdx.x * 4 + (threadIdx.x >> 6);   // 0..127
    int lane = threadIdx.x & 63;
    int l = wid >> 5;
    int b = wid & 31;
    const float* cls; const float* wc;
    if      (l == 0) { cls = c0; wc = wc0; }
    else if (l == 1) { cls = c1; wc = wc1; }
    else if (l == 2) { cls = c2; wc = wc2; }
    else             { cls = c3; wc = wc3; }
    const float* x = cls + (size_t)b * D;

    float sxx = 0.f, sx0 = 0.f, sx1 = 0.f, s00 = 0.f, s11 = 0.f;
#pragma unroll
    for (int kk = 0; kk < 4; ++kk) {
        int off = kk * 256 + lane * 4;
        const float4 v  = *reinterpret_cast<const float4*>(x + off);
        const float4 a  = *reinterpret_cast<const float4*>(wc + off);
        const float4 bb = *reinterpret_cast<const float4*>(wc + D + off);
        sxx += v.x * v.x + v.y * v.y + v.z * v.z + v.w * v.w;
        sx0 += v.x * a.x + v.y * a.y + v.z * a.z + v.w * a.w;
        sx1 += v.x * bb.x + v.y * bb.y + v.z * bb.z + v.w * bb.w;
        s00 += a.x * a.x + a.y * a.y + a.z * a.z + a.w * a.w;
        s11 += bb.x * bb.x + bb.y * bb.y + bb.z * bb.z + bb.w * bb.w;
    }
    sxx = wave_sum(sxx); sx0 = wave_sum(sx0); sx1 = wave_sum(sx1);
    s00 = wave_sum(s00); s11 = wave_sum(s11);
    if (lane == 0) {
        float invx = 1.0f / fmaxf(sqrtf(sxx), EPS_NORM);
        float iw0  = 1.0f / fmaxf(sqrtf(s00), EPS_NORM);
        float iw1  = 1.0f / fmaxf(sqrtf(s11), EPS_NORM);
        out[((size_t)l * B + b) * 2 + 0] = sx0 * invx * iw0 * TAU_INV;
        out[((size_t)l * B + b) * 2 + 1] = sx1 * invx * iw1 * TAU_INV;
    }
}

// ---------------------------------------------------------------------------
// Kernel 2: seg probabilities. 8 rows per wave, weights preloaded to regs.
// waves = 131072/8 = 16384 -> 4096 blocks x 256 (4 waves/block).
// Each wave also computes the seg-weight inverse norms itself (amortized /8).
// Writes probs laid out [L][B][2][N] as packed float4s.
// ---------------------------------------------------------------------------
__global__ __launch_bounds__(256, 4) void seg_kernel(
        const float* p0, const float* w0,
        const float* p1, const float* w1,
        const float* p2, const float* w2,
        const float* p3, const float* w3,
        float* probs) {
    int wid = blockIdx.x * 4 + (threadIdx.x >> 6);   // 0..16383
    int lane = threadIdx.x & 63;
    int base = wid * 8;          // first global row of this wave's 8 rows
    int l = base >> 15;          // 32768 rows per layer
    int rem = base & 32767;      // b*N + n0 within the layer (n0 multiple of 8)
    const float* patch; const float* wsg;
    if      (l == 0) { patch = p0; wsg = w0; }
    else if (l == 1) { patch = p1; wsg = w1; }
    else if (l == 2) { patch = p2; wsg = w2; }
    else             { patch = p3; wsg = w3; }

    // Preload both weight rows (this lane's 16 floats of each) + self-dots.
    float4 wa[4], wb[4];
    float s00 = 0.f, s11 = 0.f;
#pragma unroll
    for (int kk = 0; kk < 4; ++kk) {
        int off = kk * 256 + lane * 4;
        wa[kk] = *reinterpret_cast<const float4*>(wsg + off);
        wb[kk] = *reinterpret_cast<const float4*>(wsg + D + off);
        s00 += wa[kk].x * wa[kk].x + wa[kk].y * wa[kk].y + wa[kk].z * wa[kk].z + wa[kk].w * wa[kk].w;
        s11 += wb[kk].x * wb[kk].x + wb[kk].y * wb[kk].y + wb[kk].z * wb[kk].z + wb[kk].w * wb[kk].w;
    }
    s00 = wave_sum(s00); s11 = wave_sum(s11);
    const float iw0 = 1.0f / fmaxf(sqrtf(s00), EPS_NORM) * TAU_INV;
    const float iw1 = 1.0f / fmaxf(sqrtf(s11), EPS_NORM) * TAU_INV;

    // NOTE: index with rem (layer-local), NOT base (includes layer offset).
    const float* xb = patch + (size_t)rem * D;
    float pr0a[8], pr1a[8];
#pragma unroll
    for (int r = 0; r < 8; ++r) {
        const float* x = xb + (size_t)r * D;
        float sxx = 0.f, s0 = 0.f, s1 = 0.f;
#pragma unroll
        for (int kk = 0; kk < 4; ++kk) {
            int off = kk * 256 + lane * 4;
            const float4 v = *reinterpret_cast<const float4*>(x + off);
            sxx += v.x * v.x + v.y * v.y + v.z * v.z + v.w * v.w;
            s0  += v.x * wa[kk].x + v.y * wa[kk].y + v.z * wa[kk].z + v.w * wa[kk].w;
            s1  += v.x * wb[kk].x + v.y * wb[kk].y + v.z * wb[kk].z + v.w * wb[kk].w;
        }
        sxx = wave_sum(sxx); s0 = wave_sum(s0); s1 = wave_sum(s1);
        float invx = 1.0f / fmaxf(sqrtf(sxx), EPS_NORM);
        float l0 = s0 * invx * iw0;
        float l1 = s1 * invx * iw1;
        pr0a[r] = 1.0f / (1.0f + __expf(l1 - l0));
        pr1a[r] = 1.0f / (1.0f + __expf(l0 - l1));
    }

    if (lane == 0) {
        int b = rem >> 10, n0 = rem & 1023;
        float* o = probs + ((size_t)(l * B + b) * 2) * N;
        float4* o0 = reinterpret_cast<float4*>(o + n0);
        float4* o1 = reinterpret_cast<float4*>(o + N + n0);
        o0[0] = make_float4(pr0a[0], pr0a[1], pr0a[2], pr0a[3]);
        o0[1] = make_float4(pr0a[4], pr0a[5], pr0a[6], pr0a[7]);
        o1[0] = make_float4(pr1a[0], pr1a[1], pr1a[2], pr1a[3]);
        o1[1] = make_float4(pr1a[4], pr1a[5], pr1a[6], pr1a[7]);
    }
}

// ---------------------------------------------------------------------------
// Kernel 3: bilinear 16x upsample 32x32 -> 512x512 per image.
// 256 images (L*B*2) x 8 chunks of 64 rows -> 2048 blocks x 256.
// Per-thread x-geometry (x0/x1/wx[4]) hoisted out of the loop: xv = tid&127 is
// loop-invariant, and all 4 pixels of a float4 share one (x0,x1) pair.
// ---------------------------------------------------------------------------
__global__ __launch_bounds__(256) void upsample_kernel(const float* probs, float* out) {
    __shared__ float rowbuf[64 * 32];

    int img   = blockIdx.x >> 3;     // 0..255
    int chunk = blockIdx.x & 7;      // 0..7 (64 output rows each)
    const float* S = probs + (size_t)img * (SIDE * SIDE);

    // Stage 1: rowbuf[r][x] = y-lerp of S for output rows gy = chunk*64 + r
    for (int e = threadIdx.x; e < 64 * 32; e += 256) {
        int r = e >> 5;
        int xs = e & 31;
        int gy = chunk * 64 + r;
        float fy = fmaxf(((float)gy + 0.5f) * 0.0625f - 0.5f, 0.0f);
        int y0 = min((int)fy, SIDE - 1);
        int y1 = min(y0 + 1, SIDE - 1);
        float wy = fy - (float)y0;
        float a = S[y0 * SIDE + xs];
        float b = S[y1 * SIDE + xs];
        rowbuf[e] = a + wy * (b - a);
    }
    __syncthreads();

    // Per-thread loop-invariant x geometry
    int tid = threadIdx.x;
    int xv  = tid & 127;             // float4 column, fixed across iterations
    int rhalf = tid >> 7;            // 0/1
    float fx0 = fmaxf(((float)(4 * xv) + 0.5f) * 0.0625f - 0.5f, 0.0f);
    int x0 = min((int)fx0, SIDE - 1);
    int x1 = min(x0 + 1, SIDE - 1);
    float wx[4];
#pragma unroll
    for (int j = 0; j < 4; ++j) {
        float fx = fmaxf(((float)(4 * xv + j) + 0.5f) * 0.0625f - 0.5f, 0.0f);
        wx[j] = fx - (float)x0;
    }

    float4* obase = reinterpret_cast<float4*>(out) + (size_t)img * (OUT * OUT / 4);
#pragma unroll 8
    for (int it = 0; it < 32; ++it) {
        int r = it * 2 + rhalf;      // row within chunk
        const float* rb = rowbuf + r * 32;
        float r0 = rb[x0];
        float d  = rb[x1] - r0;
        float4 o;
        o.x = r0 + wx[0] * d;
        o.y = r0 + wx[1] * d;
        o.z = r0 + wx[2] * d;
        o.w = r0 + wx[3] * d;
        int gy = chunk * 64 + r;
        obase[(size_t)gy * (OUT / 4) + xv] = o;
    }
}

// ---------------------------------------------------------------------------
extern "C" void kernel_launch(void* const* d_in, const int* in_sizes, int n_in,
                              void* d_out, int out_size, void* d_ws, size_t ws_size,
                              hipStream_t stream) {
    const float* cls[4];  const float* patch[4];
    const float* wcls[4]; const float* wseg[4];
    for (int l = 0; l < 4; ++l) {
        cls[l]   = (const float*)d_in[4 * l + 0];
        patch[l] = (const float*)d_in[4 * l + 1];
        wcls[l]  = (const float*)d_in[4 * l + 2];
        wseg[l]  = (const float*)d_in[4 * l + 3];
    }
    float* out = (float*)d_out;            // [4,32,2] cls logits then [4,32,2,512,512]
    float* seg_out = out + NLAYER * B * 2; // offset 256 floats
    float* ws_probs = (float*)d_ws;        // [4][32][2][1024] = 1 MB

    cls_kernel<<<32, 256, 0, stream>>>(cls[0], wcls[0], cls[1], wcls[1],
                                       cls[2], wcls[2], cls[3], wcls[3], out);

    seg_kernel<<<4096, 256, 0, stream>>>(patch[0], wseg[0], patch[1], wseg[1],
                                         patch[2], wseg[2], patch[3], wseg[3],
                                         ws_probs);

    upsample_kernel<<<2048, 256, 0, stream>>>(ws_probs, seg_out);
}

// Round 4
// 181.094 us; speedup vs baseline: 1.1957x; 1.1957x over previous
//
#include <hip/hip_runtime.h>
#include <math.h>

// Problem constants (fixed by setup_inputs)
#define D 1024
#define B 32
#define N 1024          // patches per image (32x32)
#define SIDE 32
#define OUT 512
#define NLAYER 4
#define TAU_INV (1.0f/0.07f)
#define EPS_NORM 1e-12f

__device__ __forceinline__ float wave_sum(float s) {
#pragma unroll
    for (int m = 32; m; m >>= 1) s += __shfl_xor(s, m);
    return s;
}

// ---------------------------------------------------------------------------
// Kernel 1: cls logits (computes its own w_cls norms).
// One wave per (l,b) row; 128 waves -> 32 blocks x 256.
// ---------------------------------------------------------------------------
__global__ void cls_kernel(const float* c0, const float* wc0,
                           const float* c1, const float* wc1,
                           const float* c2, const float* wc2,
                           const float* c3, const float* wc3,
                           float* out) {
    int wid = blockIdx.x * 4 + (threadIdx.x >> 6);   // 0..127
    int lane = threadIdx.x & 63;
    int l = wid >> 5;
    int b = wid & 31;
    const float* cls; const float* wc;
    if      (l == 0) { cls = c0; wc = wc0; }
    else if (l == 1) { cls = c1; wc = wc1; }
    else if (l == 2) { cls = c2; wc = wc2; }
    else             { cls = c3; wc = wc3; }
    const float* x = cls + (size_t)b * D;

    float sxx = 0.f, sx0 = 0.f, sx1 = 0.f, s00 = 0.f, s11 = 0.f;
#pragma unroll
    for (int kk = 0; kk < 4; ++kk) {
        int off = kk * 256 + lane * 4;
        const float4 v  = *reinterpret_cast<const float4*>(x + off);
        const float4 a  = *reinterpret_cast<const float4*>(wc + off);
        const float4 bb = *reinterpret_cast<const float4*>(wc + D + off);
        sxx += v.x * v.x + v.y * v.y + v.z * v.z + v.w * v.w;
        sx0 += v.x * a.x + v.y * a.y + v.z * a.z + v.w * a.w;
        sx1 += v.x * bb.x + v.y * bb.y + v.z * bb.z + v.w * bb.w;
        s00 += a.x * a.x + a.y * a.y + a.z * a.z + a.w * a.w;
        s11 += bb.x * bb.x + bb.y * bb.y + bb.z * bb.z + bb.w * bb.w;
    }
    sxx = wave_sum(sxx); sx0 = wave_sum(sx0); sx1 = wave_sum(sx1);
    s00 = wave_sum(s00); s11 = wave_sum(s11);
    if (lane == 0) {
        float invx = 1.0f / fmaxf(sqrtf(sxx), EPS_NORM);
        float iw0  = 1.0f / fmaxf(sqrtf(s00), EPS_NORM);
        float iw1  = 1.0f / fmaxf(sqrtf(s11), EPS_NORM);
        out[((size_t)l * B + b) * 2 + 0] = sx0 * invx * iw0 * TAU_INV;
        out[((size_t)l * B + b) * 2 + 1] = sx1 * invx * iw1 * TAU_INV;
    }
}

// ---------------------------------------------------------------------------
// Kernel 2: seg probabilities. 4 rows per wave, weights preloaded to regs.
// waves = 131072/4 = 32768 -> 8192 blocks x 256 (4 waves/block).
// NO min-occupancy launch bound: R3 showed __launch_bounds__(256,4) forced a
// 64-VGPR allocation that spilled wa/wb/pr to scratch (WRITE_SIZE 103 MB for
// a 1 MB output, 2.3 TB/s, 186 us). Let the allocator take ~100 VGPRs.
// Writes probs laid out [L][B][2][N] as packed float4s.
// ---------------------------------------------------------------------------
__global__ __launch_bounds__(256) void seg_kernel(
        const float* p0, const float* w0,
        const float* p1, const float* w1,
        const float* p2, const float* w2,
        const float* p3, const float* w3,
        float* probs) {
    int wid = blockIdx.x * 4 + (threadIdx.x >> 6);   // 0..32767
    int lane = threadIdx.x & 63;
    int base = wid * 4;          // first global row of this wave's 4 rows
    int l = base >> 15;          // 32768 rows per layer
    int rem = base & 32767;      // b*N + n0 within the layer (n0 multiple of 4)
    const float* patch; const float* wsg;
    if      (l == 0) { patch = p0; wsg = w0; }
    else if (l == 1) { patch = p1; wsg = w1; }
    else if (l == 2) { patch = p2; wsg = w2; }
    else             { patch = p3; wsg = w3; }

    // Preload both weight rows (this lane's 16 floats of each) + self-dots.
    float4 wa[4], wb[4];
    float s00 = 0.f, s11 = 0.f;
#pragma unroll
    for (int kk = 0; kk < 4; ++kk) {
        int off = kk * 256 + lane * 4;
        wa[kk] = *reinterpret_cast<const float4*>(wsg + off);
        wb[kk] = *reinterpret_cast<const float4*>(wsg + D + off);
        s00 += wa[kk].x * wa[kk].x + wa[kk].y * wa[kk].y + wa[kk].z * wa[kk].z + wa[kk].w * wa[kk].w;
        s11 += wb[kk].x * wb[kk].x + wb[kk].y * wb[kk].y + wb[kk].z * wb[kk].z + wb[kk].w * wb[kk].w;
    }
    s00 = wave_sum(s00); s11 = wave_sum(s11);
    const float iw0 = 1.0f / fmaxf(sqrtf(s00), EPS_NORM) * TAU_INV;
    const float iw1 = 1.0f / fmaxf(sqrtf(s11), EPS_NORM) * TAU_INV;

    // Index with rem (layer-local), NOT base (includes layer offset).
    const float* xb = patch + (size_t)rem * D;
    float pr0a[4], pr1a[4];
#pragma unroll
    for (int r = 0; r < 4; ++r) {
        const float* x = xb + (size_t)r * D;
        float sxx = 0.f, s0 = 0.f, s1 = 0.f;
#pragma unroll
        for (int kk = 0; kk < 4; ++kk) {
            int off = kk * 256 + lane * 4;
            const float4 v = *reinterpret_cast<const float4*>(x + off);
            sxx += v.x * v.x + v.y * v.y + v.z * v.z + v.w * v.w;
            s0  += v.x * wa[kk].x + v.y * wa[kk].y + v.z * wa[kk].z + v.w * wa[kk].w;
            s1  += v.x * wb[kk].x + v.y * wb[kk].y + v.z * wb[kk].z + v.w * wb[kk].w;
        }
        sxx = wave_sum(sxx); s0 = wave_sum(s0); s1 = wave_sum(s1);
        float invx = 1.0f / fmaxf(sqrtf(sxx), EPS_NORM);
        float l0 = s0 * invx * iw0;
        float l1 = s1 * invx * iw1;
        pr0a[r] = 1.0f / (1.0f + __expf(l1 - l0));
        pr1a[r] = 1.0f / (1.0f + __expf(l0 - l1));
    }

    if (lane == 0) {
        int b = rem >> 10, n0 = rem & 1023;
        float* o = probs + ((size_t)(l * B + b) * 2) * N;
        *reinterpret_cast<float4*>(o + n0)     = make_float4(pr0a[0], pr0a[1], pr0a[2], pr0a[3]);
        *reinterpret_cast<float4*>(o + N + n0) = make_float4(pr1a[0], pr1a[1], pr1a[2], pr1a[3]);
    }
}

// ---------------------------------------------------------------------------
// Kernel 3: bilinear 16x upsample 32x32 -> 512x512 per image.
// 256 images (L*B*2) x 8 chunks of 64 rows -> 2048 blocks x 256.
// Per-thread x-geometry (x0/x1/wx[4]) hoisted out of the loop: xv = tid&127 is
// loop-invariant, and all 4 pixels of a float4 share one (x0,x1) pair.
// ---------------------------------------------------------------------------
__global__ __launch_bounds__(256) void upsample_kernel(const float* probs, float* out) {
    __shared__ float rowbuf[64 * 32];

    int img   = blockIdx.x >> 3;     // 0..255
    int chunk = blockIdx.x & 7;      // 0..7 (64 output rows each)
    const float* S = probs + (size_t)img * (SIDE * SIDE);

    // Stage 1: rowbuf[r][x] = y-lerp of S for output rows gy = chunk*64 + r
    for (int e = threadIdx.x; e < 64 * 32; e += 256) {
        int r = e >> 5;
        int xs = e & 31;
        int gy = chunk * 64 + r;
        float fy = fmaxf(((float)gy + 0.5f) * 0.0625f - 0.5f, 0.0f);
        int y0 = min((int)fy, SIDE - 1);
        int y1 = min(y0 + 1, SIDE - 1);
        float wy = fy - (float)y0;
        float a = S[y0 * SIDE + xs];
        float b = S[y1 * SIDE + xs];
        rowbuf[e] = a + wy * (b - a);
    }
    __syncthreads();

    // Per-thread loop-invariant x geometry
    int tid = threadIdx.x;
    int xv  = tid & 127;             // float4 column, fixed across iterations
    int rhalf = tid >> 7;            // 0/1
    float fx0 = fmaxf(((float)(4 * xv) + 0.5f) * 0.0625f - 0.5f, 0.0f);
    int x0 = min((int)fx0, SIDE - 1);
    int x1 = min(x0 + 1, SIDE - 1);
    float wx[4];
#pragma unroll
    for (int j = 0; j < 4; ++j) {
        float fx = fmaxf(((float)(4 * xv + j) + 0.5f) * 0.0625f - 0.5f, 0.0f);
        wx[j] = fx - (float)x0;
    }

    float4* obase = reinterpret_cast<float4*>(out) + (size_t)img * (OUT * OUT / 4);
#pragma unroll 8
    for (int it = 0; it < 32; ++it) {
        int r = it * 2 + rhalf;      // row within chunk
        const float* rb = rowbuf + r * 32;
        float r0 = rb[x0];
        float d  = rb[x1] - r0;
        float4 o;
        o.x = r0 + wx[0] * d;
        o.y = r0 + wx[1] * d;
        o.z = r0 + wx[2] * d;
        o.w = r0 + wx[3] * d;
        int gy = chunk * 64 + r;
        obase[(size_t)gy * (OUT / 4) + xv] = o;
    }
}

// ---------------------------------------------------------------------------
extern "C" void kernel_launch(void* const* d_in, const int* in_sizes, int n_in,
                              void* d_out, int out_size, void* d_ws, size_t ws_size,
                              hipStream_t stream) {
    const float* cls[4];  const float* patch[4];
    const float* wcls[4]; const float* wseg[4];
    for (int l = 0; l < 4; ++l) {
        cls[l]   = (const float*)d_in[4 * l + 0];
        patch[l] = (const float*)d_in[4 * l + 1];
        wcls[l]  = (const float*)d_in[4 * l + 2];
        wseg[l]  = (const float*)d_in[4 * l + 3];
    }
    float* out = (float*)d_out;            // [4,32,2] cls logits then [4,32,2,512,512]
    float* seg_out = out + NLAYER * B * 2; // offset 256 floats
    float* ws_probs = (float*)d_ws;        // [4][32][2][1024] = 1 MB

    cls_kernel<<<32, 256, 0, stream>>>(cls[0], wcls[0], cls[1], wcls[1],
                                       cls[2], wcls[2], cls[3], wcls[3], out);

    seg_kernel<<<8192, 256, 0, stream>>>(patch[0], wseg[0], patch[1], wseg[1],
                                         patch[2], wseg[2], patch[3], wseg[3],
                                         ws_probs);

    upsample_kernel<<<2048, 256, 0, stream>>>(ws_probs, seg_out);
}